// Round 1
// 1482.481 us; speedup vs baseline: 1.9166x; 1.9166x over previous
//
#include <hip/hip_runtime.h>
#include <hip/hip_bf16.h>

#define N_NODES 100000
#define N_EDGES 500000
#define DIM 256
#define NH 8
#define DH 32

typedef short short8 __attribute__((ext_vector_type(8)));
typedef float f32x4 __attribute__((ext_vector_type(4)));

__device__ __forceinline__ unsigned short f2bf(float f) {
    unsigned u = __float_as_uint(f);
    unsigned r = (u + 0x7FFFu + ((u >> 16) & 1u)) >> 16;  // RNE
    return (unsigned short)r;
}
__device__ __forceinline__ float bf2f(unsigned short u) {
    return __uint_as_float(((unsigned)u) << 16);
}

// ---- transpose + bf16-cast a 256x256 weight matrix: WT[n][k] = W[k][n] ----
__global__ __launch_bounds__(256) void wconvert(const float* __restrict__ W,
                                                unsigned short* __restrict__ WT) {
    int t = blockIdx.x * 256 + threadIdx.x;  // 65536 threads
    int n = t >> 8, k = t & 255;
    WT[n * 256 + k] = f2bf(W[k * 256 + n]);
}

// ---- C[M,256](bf16) = A[M,256](f32) @ B[256,256], B given transposed as WT[n][k] bf16 ----
__global__ __launch_bounds__(256) void gemm_bf16(const float* __restrict__ A,
                                                 const unsigned short* __restrict__ WT,
                                                 unsigned short* __restrict__ C, int M) {
    __shared__ unsigned short Blds[256 * 32];  // WT chunk for current kc: [n][32k] = 16KB
    const int tid = threadIdx.x;
    const int wave = tid >> 6, lane = tid & 63;
    const int quad = lane >> 4, col = lane & 15;
    const int base = blockIdx.x * 64 + wave * 16;
    const int arow = min(base + col, M - 1);  // clamped load row (stores are guarded)

    f32x4 acc[16];
#pragma unroll
    for (int i = 0; i < 16; i++) acc[i] = (f32x4){0.f, 0.f, 0.f, 0.f};

    for (int kc = 0; kc < 8; kc++) {
        __syncthreads();
#pragma unroll
        for (int it = 0; it < 4; it++) {
            int e = it * 2048 + tid * 8;
            int n = e >> 5, j = e & 31;
            *(short8*)(&Blds[n * 32 + j]) = *(const short8*)(&WT[n * 256 + kc * 32 + j]);
        }
        __syncthreads();
        const float* ap = A + (long)arow * 256 + kc * 32 + quad * 8;
        float4 a0 = *(const float4*)ap;
        float4 a1 = *(const float4*)(ap + 4);
        short8 af;
        af[0] = f2bf(a0.x); af[1] = f2bf(a0.y); af[2] = f2bf(a0.z); af[3] = f2bf(a0.w);
        af[4] = f2bf(a1.x); af[5] = f2bf(a1.y); af[6] = f2bf(a1.z); af[7] = f2bf(a1.w);
#pragma unroll
        for (int nt = 0; nt < 16; nt++) {
            short8 bf = *(const short8*)(&Blds[(nt * 16 + col) * 32 + quad * 8]);
            acc[nt] = __builtin_amdgcn_mfma_f32_16x16x32_bf16(af, bf, acc[nt], 0, 0, 0);
        }
    }
#pragma unroll
    for (int nt = 0; nt < 16; nt++) {
#pragma unroll
        for (int r = 0; r < 4; r++) {
            int orow = base + quad * 4 + r;
            if (orow < M) C[(long)orow * 256 + nt * 16 + col] = f2bf(acc[nt][r]);
        }
    }
}

// ---- CSR build: histogram of dst ----
__global__ __launch_bounds__(256) void hist_kernel(const int* __restrict__ ei,
                                                   int* __restrict__ counts) {
    int e = blockIdx.x * 256 + threadIdx.x;
    if (e < N_EDGES) atomicAdd(&counts[ei[N_EDGES + e]], 1);
}

// ---- CSR build: exclusive scan of counts (single block, 1024 threads) ----
__global__ __launch_bounds__(1024) void scan_kernel(const int* __restrict__ counts,
                                                    int* __restrict__ offs,
                                                    int* __restrict__ cursor) {
    __shared__ int tsum[1024];
    const int t = threadIdx.x;
    const int CH = (N_NODES + 1023) / 1024;  // 98
    int lo = t * CH;
    int hi = min(lo + CH, N_NODES);
    int s = 0;
    for (int i = lo; i < hi; i++) s += counts[i];
    tsum[t] = s;
    __syncthreads();
    // Kogge-Stone inclusive scan over 1024 thread sums
    for (int d = 1; d < 1024; d <<= 1) {
        int v = (t >= d) ? tsum[t - d] : 0;
        __syncthreads();
        tsum[t] += v;
        __syncthreads();
    }
    int run = (t == 0) ? 0 : tsum[t - 1];  // exclusive prefix for this chunk
    for (int i = lo; i < hi; i++) {
        offs[i] = run;
        cursor[i] = run;
        run += counts[i];
    }
    if (t == 1023) offs[N_NODES] = run;  // == N_EDGES
}

// ---- CSR build: scatter (edge, src) pairs grouped by dst ----
__global__ __launch_bounds__(256) void scatter_kernel(const int* __restrict__ ei,
                                                      int* __restrict__ cursor,
                                                      int2* __restrict__ epair) {
    int e = blockIdx.x * 256 + threadIdx.x;
    if (e >= N_EDGES) return;
    int dst = ei[N_EDGES + e];
    int pos = atomicAdd(&cursor[dst], 1);
    epair[pos] = make_int2(e, ei[e]);
}

// ---- fused: per-node gather-attention + residual + BN column stats ----
// One wave per node; lane owns dims [4*lane, 4*lane+4), head = lane>>3.
__global__ __launch_bounds__(256) void node_kernel(const unsigned short* __restrict__ Qb,
                                                   const unsigned short* __restrict__ Kb,
                                                   const unsigned short* __restrict__ Vb,
                                                   const unsigned short* __restrict__ Ehb,
                                                   const float* __restrict__ x,
                                                   const int* __restrict__ offs,
                                                   const int2* __restrict__ epair,
                                                   float* __restrict__ h,
                                                   float* __restrict__ csum,
                                                   float* __restrict__ csumsq) {
    __shared__ float lsum[256], lss[256];
    const int wave = threadIdx.x >> 6, lane = threadIdx.x & 63;
    lsum[threadIdx.x] = 0.f;
    lss[threadIdx.x] = 0.f;
    __syncthreads();

    float s0 = 0.f, s1 = 0.f, s2 = 0.f, s3 = 0.f;      // column sums (4 cols/lane)
    float q0 = 0.f, q1 = 0.f, q2 = 0.f, q3 = 0.f;      // column sumsq

    for (int n = blockIdx.x * 4 + wave; n < N_NODES; n += gridDim.x * 4) {
        ushort4 qv = ((const ushort4*)(Qb + (long)n * 256))[lane];
        float qx = bf2f(qv.x), qy = bf2f(qv.y), qz = bf2f(qv.z), qw = bf2f(qv.w);
        f32x4 acc = (f32x4){0.f, 0.f, 0.f, 0.f};
        float zh = 0.f;
        const int beg = offs[n], end = offs[n + 1];
        for (int idx = beg; idx < end; idx++) {
            int2 p = epair[idx];                 // (edge, src) — wave-uniform broadcast
            const long eoff = (long)p.x * 256;
            const long soff = (long)p.y * 256;
            ushort4 k4 = ((const ushort4*)(Kb + soff))[lane];
            ushort4 e4 = ((const ushort4*)(Ehb + eoff))[lane];
            ushort4 v4 = ((const ushort4*)(Vb + soff))[lane];
            float s = bf2f(k4.x) * qx * bf2f(e4.x)
                    + bf2f(k4.y) * qy * bf2f(e4.y)
                    + bf2f(k4.z) * qz * bf2f(e4.z)
                    + bf2f(k4.w) * qw * bf2f(e4.w);
            // reduce over the 8 lanes of this head
            s += __shfl_xor(s, 1);
            s += __shfl_xor(s, 2);
            s += __shfl_xor(s, 4);
            s *= 0.17677669529663687f;  // 1/sqrt(32)
            s = fminf(fmaxf(s, -5.f), 5.f);
            float sc = __expf(s);
            acc[0] += bf2f(v4.x) * sc;
            acc[1] += bf2f(v4.y) * sc;
            acc[2] += bf2f(v4.z) * sc;
            acc[3] += bf2f(v4.w) * sc;
            zh += sc;
        }
        float inv = 1.f / (zh + 1e-6f);
        float4 xv = *(const float4*)(x + (long)n * 256 + lane * 4);
        float o0 = xv.x + acc[0] * inv;
        float o1 = xv.y + acc[1] * inv;
        float o2 = xv.z + acc[2] * inv;
        float o3 = xv.w + acc[3] * inv;
        float4 ov = {o0, o1, o2, o3};
        *(float4*)(h + (long)n * 256 + lane * 4) = ov;
        s0 += o0; s1 += o1; s2 += o2; s3 += o3;
        q0 += o0 * o0; q1 += o1 * o1; q2 += o2 * o2; q3 += o3 * o3;
    }

    // block-level reduction of BN stats, then one global atomic per column
    int c = lane * 4;
    atomicAdd(&lsum[c + 0], s0); atomicAdd(&lss[c + 0], q0);
    atomicAdd(&lsum[c + 1], s1); atomicAdd(&lss[c + 1], q1);
    atomicAdd(&lsum[c + 2], s2); atomicAdd(&lss[c + 2], q2);
    atomicAdd(&lsum[c + 3], s3); atomicAdd(&lss[c + 3], q3);
    __syncthreads();
    atomicAdd(&csum[threadIdx.x], lsum[threadIdx.x]);
    atomicAdd(&csumsq[threadIdx.x], lss[threadIdx.x]);
}

// ---- BN pass 2: normalize in place ----
__global__ __launch_bounds__(256) void bn_pass2(float* __restrict__ h,
                                                const float* __restrict__ csum,
                                                const float* __restrict__ csumsq,
                                                const float* __restrict__ gamma,
                                                const float* __restrict__ beta) {
    const float invN = 1.0f / N_NODES;
    const long total = (long)N_NODES * 256;
    for (long i = (long)blockIdx.x * 256 + threadIdx.x; i < total; i += (long)gridDim.x * 256) {
        int c = (int)(i & 255);
        float mean = csum[c] * invN;
        float var = csumsq[c] * invN - mean * mean;
        h[i] = (h[i] - mean) * rsqrtf(var + 1e-5f) * gamma[c] + beta[c];
    }
}

extern "C" void kernel_launch(void* const* d_in, const int* in_sizes, int n_in,
                              void* d_out, int out_size, void* d_ws, size_t ws_size,
                              hipStream_t stream) {
    const float* x     = (const float*)d_in[0];
    const float* ea    = (const float*)d_in[1];
    const float* WQ    = (const float*)d_in[2];
    const float* WK    = (const float*)d_in[3];
    const float* WE    = (const float*)d_in[4];  // note: WE before WV in dict order
    const float* WV    = (const float*)d_in[5];
    const float* gamma = (const float*)d_in[6];
    const float* beta  = (const float*)d_in[7];
    const int*   ei    = (const int*)d_in[8];
    float* out = (float*)d_out;

    char* ws = (char*)d_ws;
    size_t off = 0;
    auto alloc = [&](size_t bytes) -> void* {
        void* p = ws + off;
        off = (off + bytes + 255) & ~(size_t)255;
        return p;
    };
    unsigned short* WTq = (unsigned short*)alloc(65536 * 2);
    unsigned short* WTk = (unsigned short*)alloc(65536 * 2);
    unsigned short* WTe = (unsigned short*)alloc(65536 * 2);
    unsigned short* WTv = (unsigned short*)alloc(65536 * 2);
    unsigned short* Qb  = (unsigned short*)alloc((size_t)N_NODES * 256 * 2);
    unsigned short* Kb  = (unsigned short*)alloc((size_t)N_NODES * 256 * 2);
    unsigned short* Vb  = (unsigned short*)alloc((size_t)N_NODES * 256 * 2);
    unsigned short* Ehb = (unsigned short*)alloc((size_t)N_EDGES * 256 * 2);
    // zero region: counts + csum + csumsq contiguous
    int*   counts = (int*)alloc((size_t)N_NODES * 4);
    float* csum   = (float*)alloc(256 * 4);
    float* csumsq = (float*)alloc(256 * 4);
    char*  zend   = ws + off;
    int*   offs   = (int*)alloc((size_t)(N_NODES + 1) * 4);
    int*   cursor = (int*)alloc((size_t)N_NODES * 4);
    int2*  epair  = (int2*)alloc((size_t)N_EDGES * 8);

    // weight transpose + cast (tiny)
    wconvert<<<256, 256, 0, stream>>>(WQ, WTq);
    wconvert<<<256, 256, 0, stream>>>(WK, WTk);
    wconvert<<<256, 256, 0, stream>>>(WE, WTe);
    wconvert<<<256, 256, 0, stream>>>(WV, WTv);

    // zero counters (counts + csum + csumsq in one memset)
    hipMemsetAsync(counts, 0, (size_t)(zend - (char*)counts), stream);

    // CSR build (independent of projections)
    hist_kernel<<<(N_EDGES + 255) / 256, 256, 0, stream>>>(ei, counts);
    scan_kernel<<<1, 1024, 0, stream>>>(counts, offs, cursor);
    scatter_kernel<<<(N_EDGES + 255) / 256, 256, 0, stream>>>(ei, cursor, epair);

    // projections
    gemm_bf16<<<(N_NODES + 63) / 64, 256, 0, stream>>>(x, WTq, Qb, N_NODES);
    gemm_bf16<<<(N_NODES + 63) / 64, 256, 0, stream>>>(x, WTk, Kb, N_NODES);
    gemm_bf16<<<(N_NODES + 63) / 64, 256, 0, stream>>>(x, WTv, Vb, N_NODES);
    gemm_bf16<<<(N_EDGES + 63) / 64, 256, 0, stream>>>(ea, WTe, Ehb, N_EDGES);

    // fused gather-attention + residual + BN stats
    node_kernel<<<2048, 256, 0, stream>>>(Qb, Kb, Vb, Ehb, x, offs, epair,
                                          out, csum, csumsq);

    // normalize
    bn_pass2<<<4096, 256, 0, stream>>>(out, csum, csumsq, gamma, beta);
}